// Round 8
// baseline (467.576 us; speedup 1.0000x reference)
//
#include <hip/hip_runtime.h>
#include <stdint.h>

// Dyna_Dec: out[b,d,l] = sum_c x[b,c,l] * w[l,c,d] + bias[l,d]
// B=128, C=32, L=4096, fp32 in/out.
//
// R7 post-mortem: LDS-staged version 110us — WRITE doubled to 132MB
// (nontemporal epilogue / scratch round-trip; VGPR=64 can't hold acc) and
// 16 __syncthreads drained vmcnt(0), breaking the x prefetch pipeline.
// R6 (88us) showed the real enemy is the lane-scattered W gather.
//
// R8: two kernels. (1) transpose W [L, C*C] -> WT [C*C, L] (33MB traffic,
// ~7us) into d_ws. (2) compute = R6 structure but ALL streams coalesced
// (x, WT, out), no LDS, no barriers, x+W double-buffered across c so the
// inner loop never waits on a just-issued load. Plain stores (R6's WRITE
// was exactly 64MiB). Fallback to gather kernel if ws_size < 16MiB.

namespace {

constexpr int kC  = 32;
constexpr int kL  = 4096;
constexpr int kCD = kC * kC;  // 1024
constexpr int kNB = 8;        // batches per thread
constexpr int kND = 8;        // d per thread

// ---------------- kernel 1: W transpose ----------------
// view W as A[L=4096][CD=1024]; write WT[CD][L].
__global__ __launch_bounds__(256)
void transpose_w(const float* __restrict__ w, float* __restrict__ wt) {
    __shared__ float tile[64][65];
    const int tx = threadIdx.x & 63;
    const int tg = threadIdx.x >> 6;          // 0..3
    const int cd0 = blockIdx.x * 64;          // gridDim.x = 1024/64 = 16
    const int l0  = blockIdx.y * 64;          // gridDim.y = 4096/64 = 64

#pragma unroll
    for (int k = 0; k < 16; ++k) {
        const int r = tg * 16 + k;            // l within tile
        tile[r][tx] = w[(size_t)(l0 + r) * kCD + cd0 + tx];  // coalesced over cd
    }
    __syncthreads();
#pragma unroll
    for (int k = 0; k < 16; ++k) {
        const int r = tg * 16 + k;            // cd within tile
        wt[(size_t)(cd0 + r) * kL + l0 + tx] = tile[tx][r];  // coalesced over l
    }
}

// ---------------- kernel 2: compute (WT path, all-coalesced) ----------------
__global__ __launch_bounds__(256, 4)
void dyna_dec_t(const float* __restrict__ x,
                const float* __restrict__ wt,
                const float* __restrict__ bias,
                float* __restrict__ out) {
    const int lt = threadIdx.x & 63;
    const int dg = threadIdx.x >> 6;
    const int l  = blockIdx.x * 64 + lt;      // gridDim.x = 64
    const int b0 = blockIdx.y * kNB;          // gridDim.y = 16
    const int d0 = dg * kND;

    const float* xp = x  + (size_t)b0 * (kC * kL) + l;  // + i*C*L + c*L
    const float* wp = wt + (size_t)d0 * kL + l;         // + (c*32 + j)*L

    float acc[kNB][kND];
#pragma unroll
    for (int i = 0; i < kNB; ++i)
#pragma unroll
        for (int j = 0; j < kND; ++j) acc[i][j] = 0.0f;

    float xr[2][kNB], wr[2][kND];
#pragma unroll
    for (int i = 0; i < kNB; ++i) xr[0][i] = xp[(size_t)i * (kC * kL)];
#pragma unroll
    for (int j = 0; j < kND; ++j) wr[0][j] = wp[(size_t)j * kL];

#pragma unroll 4
    for (int c = 0; c < kC; ++c) {
        const int cur = c & 1, nxt = cur ^ 1;
        if (c + 1 < kC) {  // issue next-c loads before touching cur values
#pragma unroll
            for (int i = 0; i < kNB; ++i)
                xr[nxt][i] = xp[(size_t)i * (kC * kL) + (size_t)(c + 1) * kL];
#pragma unroll
            for (int j = 0; j < kND; ++j)
                wr[nxt][j] = wp[(size_t)((c + 1) * kC + j) * kL];
        }
#pragma unroll
        for (int i = 0; i < kNB; ++i)
#pragma unroll
            for (int j = 0; j < kND; ++j)
                acc[i][j] += xr[cur][i] * wr[cur][j];
    }

    // bias[l, d0..d0+7]: one-time 2x float4 gather
    const float4 bv0 = *reinterpret_cast<const float4*>(bias + (size_t)l * kC + d0);
    const float4 bv1 = *reinterpret_cast<const float4*>(bias + (size_t)l * kC + d0 + 4);
    const float bb[kND] = {bv0.x, bv0.y, bv0.z, bv0.w,
                           bv1.x, bv1.y, bv1.z, bv1.w};

#pragma unroll
    for (int i = 0; i < kNB; ++i) {
        float* op = out + ((size_t)(b0 + i) * kC + d0) * kL + l;
#pragma unroll
        for (int j = 0; j < kND; ++j)
            op[(size_t)j * kL] = acc[i][j] + bb[j];  // coalesced over l
    }
}

// ---------------- fallback: R6 gather kernel (no workspace) ----------------
__global__ __launch_bounds__(256, 4)
void dyna_dec_gather(const float* __restrict__ x,
                     const float* __restrict__ w,
                     const float* __restrict__ bias,
                     float* __restrict__ out) {
    const int lt = threadIdx.x & 63;
    const int dg = threadIdx.x >> 6;
    const int l  = blockIdx.x * 64 + lt;
    const int b0 = blockIdx.y * kNB;
    const int d0 = dg * kND;

    const float* wp = w + (size_t)l * kCD + d0;
    const float* xp = x + (size_t)b0 * (kC * kL) + l;

    float acc[kNB][kND];
#pragma unroll
    for (int i = 0; i < kNB; ++i)
#pragma unroll
        for (int j = 0; j < kND; ++j) acc[i][j] = 0.0f;

#pragma unroll 2
    for (int c = 0; c < kC; ++c) {
        const float4 w0 = *reinterpret_cast<const float4*>(wp + c * kC);
        const float4 w1 = *reinterpret_cast<const float4*>(wp + c * kC + 4);
        const float ws[kND] = {w0.x, w0.y, w0.z, w0.w, w1.x, w1.y, w1.z, w1.w};
        float xr[kNB];
#pragma unroll
        for (int i = 0; i < kNB; ++i)
            xr[i] = xp[(size_t)i * (kC * kL) + (size_t)c * kL];
#pragma unroll
        for (int i = 0; i < kNB; ++i)
#pragma unroll
            for (int j = 0; j < kND; ++j)
                acc[i][j] += xr[i] * ws[j];
    }

    const float4 bv0 = *reinterpret_cast<const float4*>(bias + (size_t)l * kC + d0);
    const float4 bv1 = *reinterpret_cast<const float4*>(bias + (size_t)l * kC + d0 + 4);
    const float bb[kND] = {bv0.x, bv0.y, bv0.z, bv0.w,
                           bv1.x, bv1.y, bv1.z, bv1.w};
#pragma unroll
    for (int i = 0; i < kNB; ++i) {
        float* op = out + ((size_t)(b0 + i) * kC + d0) * kL + l;
#pragma unroll
        for (int j = 0; j < kND; ++j)
            op[(size_t)j * kL] = acc[i][j] + bb[j];
    }
}

}  // namespace

extern "C" void kernel_launch(void* const* d_in, const int* in_sizes, int n_in,
                              void* d_out, int out_size, void* d_ws, size_t ws_size,
                              hipStream_t stream) {
    // inputs: 0=x (B,C,H,W) fp32, 1=px (unused), 2=weight (L*C, C) fp32,
    //         3=bias (L*C) fp32
    const float* x    = (const float*)d_in[0];
    const float* wgt  = (const float*)d_in[2];
    const float* bias = (const float*)d_in[3];
    float* out = (float*)d_out;

    const size_t wt_bytes = (size_t)kCD * kL * sizeof(float);  // 16 MiB
    if (ws_size >= wt_bytes) {
        float* wt = (float*)d_ws;
        hipLaunchKernelGGL(transpose_w, dim3(kCD / 64, kL / 64), dim3(256),
                           0, stream, wgt, wt);
        hipLaunchKernelGGL(dyna_dec_t, dim3(kL / 64, 128 / kNB), dim3(256),
                           0, stream, x, wt, bias, out);
    } else {
        hipLaunchKernelGGL(dyna_dec_gather, dim3(kL / 64, 128 / kNB), dim3(256),
                           0, stream, x, wgt, bias, out);
    }
}

// Round 9
// 181.452 us; speedup vs baseline: 2.5769x; 2.5769x over previous
//
#include <hip/hip_runtime.h>
#include <stdint.h>

// Dyna_Dec: out[b,d,l] = sum_c x[b,c,l] * w[l,c,d] + bias[l,d]
// B=128, C=32, L=4096, fp32 in/out.
//
// Evidence log:
//  - dur_us = hot kernels + ~92us fixed harness overhead (R5..R8 all show
//    the same 92us delta).
//  - R6 (gather, clean regs): 88us, wall = lane-scattered W gather.
//  - R8 (WT + ping-pong ARRAYS indexed by runtime cur/nxt): FETCH 472MB /
//    WRITE 880MB / VALU 0.3% -> dynamically-indexed local arrays landed in
//    SCRATCH; every FMA round-tripped memory. VGPR=64 was the symptom.
//
// R9: same two-pass plan (transpose W -> WT[c*32+d][l], then all-coalesced
// compute), but ping-pong via two separate literal-indexed arrays (xa/xb,
// wa/wb) in fully-unrolled bodies — the R6 discipline that kept WRITE at
// exactly 64MiB. Plain stores. launch_bounds(256,4): ~111 live regs < 128.

namespace {

constexpr int kC  = 32;
constexpr int kL  = 4096;
constexpr int kCD = kC * kC;  // 1024
constexpr int kNB = 8;        // batches per thread
constexpr int kND = 8;        // d per thread

// ---------------- kernel 1: W transpose ----------------
// view W as A[L=4096][CD=1024]; write WT[CD][L]. (R8-proven correct, <10us)
__global__ __launch_bounds__(256)
void transpose_w(const float* __restrict__ w, float* __restrict__ wt) {
    __shared__ float tile[64][65];
    const int tx = threadIdx.x & 63;
    const int tg = threadIdx.x >> 6;          // 0..3
    const int cd0 = blockIdx.x * 64;          // gridDim.x = 16
    const int l0  = blockIdx.y * 64;          // gridDim.y = 64

#pragma unroll
    for (int k = 0; k < 16; ++k) {
        const int r = tg * 16 + k;            // l within tile
        tile[r][tx] = w[(size_t)(l0 + r) * kCD + cd0 + tx];  // coalesced over cd
    }
    __syncthreads();
#pragma unroll
    for (int k = 0; k < 16; ++k) {
        const int r = tg * 16 + k;            // cd within tile
        wt[(size_t)(cd0 + r) * kL + l0 + tx] = tile[tx][r];  // coalesced over l
    }
}

// ---------------- kernel 2: compute (all streams coalesced) ----------------
__global__ __launch_bounds__(256, 4)
void dyna_dec_t(const float* __restrict__ x,
                const float* __restrict__ wt,
                const float* __restrict__ bias,
                float* __restrict__ out) {
    const int lt = threadIdx.x & 63;
    const int dg = threadIdx.x >> 6;
    const int l  = blockIdx.y * 64 + lt;      // gridDim.y = 64 (l-chunks)
    const int b0 = blockIdx.x * kNB;          // gridDim.x = 16 (b-blocks share WT slice, run together)
    const int d0 = dg * kND;

    const float* xp = x  + (size_t)b0 * (kC * kL) + l;  // + i*C*L + c*L
    const float* wp = wt + (size_t)d0 * kL + l;         // + (c*32 + j)*L

    float acc[kNB][kND];
#pragma unroll
    for (int i = 0; i < kNB; ++i)
#pragma unroll
        for (int j = 0; j < kND; ++j) acc[i][j] = 0.0f;

    float xa[kNB], xb[kNB], wa[kND], wb[kND];

    // preload A := c=0
#pragma unroll
    for (int i = 0; i < kNB; ++i) xa[i] = xp[(size_t)i * (kC * kL)];
#pragma unroll
    for (int j = 0; j < kND; ++j) wa[j] = wp[(size_t)j * kL];

    // steady state: A holds c; issue B(c+1), FMA A, issue A(c+2), FMA B.
    for (int c = 0; c < kC - 2; c += 2) {
#pragma unroll
        for (int i = 0; i < kNB; ++i)
            xb[i] = xp[(size_t)i * (kC * kL) + (size_t)(c + 1) * kL];
#pragma unroll
        for (int j = 0; j < kND; ++j)
            wb[j] = wp[(size_t)((c + 1) * kC + j) * kL];
#pragma unroll
        for (int i = 0; i < kNB; ++i)
#pragma unroll
            for (int j = 0; j < kND; ++j)
                acc[i][j] += xa[i] * wa[j];
#pragma unroll
        for (int i = 0; i < kNB; ++i)
            xa[i] = xp[(size_t)i * (kC * kL) + (size_t)(c + 2) * kL];
#pragma unroll
        for (int j = 0; j < kND; ++j)
            wa[j] = wp[(size_t)((c + 2) * kC + j) * kL];
#pragma unroll
        for (int i = 0; i < kNB; ++i)
#pragma unroll
            for (int j = 0; j < kND; ++j)
                acc[i][j] += xb[i] * wb[j];
    }
    // tail: A holds c=30; load B(31), FMA A, FMA B.
#pragma unroll
    for (int i = 0; i < kNB; ++i)
        xb[i] = xp[(size_t)i * (kC * kL) + (size_t)31 * kL];
#pragma unroll
    for (int j = 0; j < kND; ++j)
        wb[j] = wp[(size_t)(31 * kC + j) * kL];
#pragma unroll
    for (int i = 0; i < kNB; ++i)
#pragma unroll
        for (int j = 0; j < kND; ++j)
            acc[i][j] += xa[i] * wa[j];
#pragma unroll
    for (int i = 0; i < kNB; ++i)
#pragma unroll
        for (int j = 0; j < kND; ++j)
            acc[i][j] += xb[i] * wb[j];

    // bias[l, d0..d0+7]
    const float4 bv0 = *reinterpret_cast<const float4*>(bias + (size_t)l * kC + d0);
    const float4 bv1 = *reinterpret_cast<const float4*>(bias + (size_t)l * kC + d0 + 4);
    const float bb[kND] = {bv0.x, bv0.y, bv0.z, bv0.w,
                           bv1.x, bv1.y, bv1.z, bv1.w};

#pragma unroll
    for (int i = 0; i < kNB; ++i) {
        float* op = out + ((size_t)(b0 + i) * kC + d0) * kL + l;
#pragma unroll
        for (int j = 0; j < kND; ++j)
            op[(size_t)j * kL] = acc[i][j] + bb[j];  // plain store, coalesced over l
    }
}

// ---------------- fallback: R6 gather kernel (no workspace) ----------------
__global__ __launch_bounds__(256, 4)
void dyna_dec_gather(const float* __restrict__ x,
                     const float* __restrict__ w,
                     const float* __restrict__ bias,
                     float* __restrict__ out) {
    const int lt = threadIdx.x & 63;
    const int dg = threadIdx.x >> 6;
    const int l  = blockIdx.x * 64 + lt;
    const int b0 = blockIdx.y * kNB;
    const int d0 = dg * kND;

    const float* wp = w + (size_t)l * kCD + d0;
    const float* xp = x + (size_t)b0 * (kC * kL) + l;

    float acc[kNB][kND];
#pragma unroll
    for (int i = 0; i < kNB; ++i)
#pragma unroll
        for (int j = 0; j < kND; ++j) acc[i][j] = 0.0f;

#pragma unroll 2
    for (int c = 0; c < kC; ++c) {
        const float4 w0 = *reinterpret_cast<const float4*>(wp + c * kC);
        const float4 w1 = *reinterpret_cast<const float4*>(wp + c * kC + 4);
        const float ws[kND] = {w0.x, w0.y, w0.z, w0.w, w1.x, w1.y, w1.z, w1.w};
        float xr[kNB];
#pragma unroll
        for (int i = 0; i < kNB; ++i)
            xr[i] = xp[(size_t)i * (kC * kL) + (size_t)c * kL];
#pragma unroll
        for (int i = 0; i < kNB; ++i)
#pragma unroll
            for (int j = 0; j < kND; ++j)
                acc[i][j] += xr[i] * ws[j];
    }

    const float4 bv0 = *reinterpret_cast<const float4*>(bias + (size_t)l * kC + d0);
    const float4 bv1 = *reinterpret_cast<const float4*>(bias + (size_t)l * kC + d0 + 4);
    const float bb[kND] = {bv0.x, bv0.y, bv0.z, bv0.w,
                           bv1.x, bv1.y, bv1.z, bv1.w};
#pragma unroll
    for (int i = 0; i < kNB; ++i) {
        float* op = out + ((size_t)(b0 + i) * kC + d0) * kL + l;
#pragma unroll
        for (int j = 0; j < kND; ++j)
            op[(size_t)j * kL] = acc[i][j] + bb[j];
    }
}

}  // namespace

extern "C" void kernel_launch(void* const* d_in, const int* in_sizes, int n_in,
                              void* d_out, int out_size, void* d_ws, size_t ws_size,
                              hipStream_t stream) {
    // inputs: 0=x (B,C,H,W) fp32, 1=px (unused), 2=weight (L*C, C) fp32,
    //         3=bias (L*C) fp32
    const float* x    = (const float*)d_in[0];
    const float* wgt  = (const float*)d_in[2];
    const float* bias = (const float*)d_in[3];
    float* out = (float*)d_out;

    const size_t wt_bytes = (size_t)kCD * kL * sizeof(float);  // 16 MiB
    if (ws_size >= wt_bytes) {
        float* wt = (float*)d_ws;
        hipLaunchKernelGGL(transpose_w, dim3(kCD / 64, kL / 64), dim3(256),
                           0, stream, wgt, wt);
        hipLaunchKernelGGL(dyna_dec_t, dim3(128 / kNB, kL / 64), dim3(256),
                           0, stream, x, wt, bias, out);
    } else {
        hipLaunchKernelGGL(dyna_dec_gather, dim3(kL / 64, 128 / kNB), dim3(256),
                           0, stream, x, wgt, bias, out);
    }
}